// Round 4
// baseline (493.354 us; speedup 1.0000x reference)
//
#include <hip/hip_runtime.h>
#include <hip/hip_bf16.h>
#include <stdint.h>

// ---------------------------------------------------------------------------
// UNetAttention: hs(2,4096,1280) fp32; self-attention H=8, D=160; out fp32.
// All matmuls via mfma_f32_16x16x32_bf16 (fp32 accum).
// ---------------------------------------------------------------------------

using bf16x8 = __attribute__((ext_vector_type(8))) short;  // 8 bf16 in 4 VGPRs
using f32x4  = __attribute__((ext_vector_type(4))) float;  // MFMA C/D frag

__device__ __forceinline__ short f2bf(float f) {
    union { float f; uint32_t u; } v; v.f = f;
    uint32_t r = v.u + 0x7fffu + ((v.u >> 16) & 1u);   // RNE
    return (short)(r >> 16);
}

// async global->LDS DMA, 16B per lane.  LDS dest = wave-uniform base + lane*16.
__device__ __forceinline__ void async16(const short* g, short* l) {
    __builtin_amdgcn_global_load_lds(
        (const __attribute__((address_space(1))) void*)g,
        (__attribute__((address_space(3))) void*)l, 16, 0, 0);
}

// ---------------------------------------------------------------------------
// hs fp32 -> bf16 (row-major, for DMA-staged QKV GEMM A)
// ---------------------------------------------------------------------------
__global__ __launch_bounds__(256) void cast_hs(
    const float* __restrict__ hs, short* __restrict__ out)
{
    int i = (blockIdx.x * 256 + threadIdx.x) * 4;
    float4 v = *(const float4*)&hs[i];
    short4 s; s.x = f2bf(v.x); s.y = f2bf(v.y); s.z = f2bf(v.z); s.w = f2bf(v.w);
    *(short4*)&out[i] = s;
}

// ---------------------------------------------------------------------------
// Weight transpose+cast: w[k][n] fp32 -> wT[n][k] bf16.
// ---------------------------------------------------------------------------
__global__ __launch_bounds__(256) void transpose_w(
    const float* __restrict__ w0, const float* __restrict__ w1,
    const float* __restrict__ w2, const float* __restrict__ w3,
    short* __restrict__ wqkvT, short* __restrict__ woutT)
{
    __shared__ float tile[32][33];
    int z = blockIdx.z;
    const float* src = (z == 0) ? w0 : (z == 1) ? w1 : (z == 2) ? w2 : w3;
    short* dst = (z == 3) ? woutT : (wqkvT + (long)z * 1280 * 1280);
    int k0 = blockIdx.x * 32, n0 = blockIdx.y * 32;
    int t = threadIdx.x, r = t >> 5, c = t & 31;
#pragma unroll
    for (int i = 0; i < 4; i++)
        tile[r + i * 8][c] = src[(long)(k0 + r + i * 8) * 1280 + n0 + c];
    __syncthreads();
#pragma unroll
    for (int i = 0; i < 4; i++)
        dst[(long)(n0 + r + i * 8) * 1280 + k0 + c] = f2bf(tile[c][r + i * 8]);
}

// ---------------------------------------------------------------------------
// v_h [bh][4096][160] bf16 -> v_t [bh][160][4096] bf16
// ---------------------------------------------------------------------------
__global__ __launch_bounds__(256) void transpose_v(
    const short* __restrict__ v, short* __restrict__ vt)
{
    __shared__ short tile[32][33];
    int s0 = blockIdx.x * 32, d0 = blockIdx.y * 32;
    long bh = blockIdx.z;
    const short* src = v + bh * 4096 * 160;
    short* dst = vt + bh * 160 * 4096;
    int t = threadIdx.x, r = t >> 5, c = t & 31;
#pragma unroll
    for (int i = 0; i < 4; i++)
        tile[r + i * 8][c] = src[(s0 + r + i * 8) * 160 + d0 + c];
    __syncthreads();
#pragma unroll
    for (int i = 0; i < 4; i++)
        dst[(d0 + r + i * 8) * 4096 + s0 + c] = tile[c][r + i * 8];
}

// ---------------------------------------------------------------------------
// 128x128 MFMA GEMM, BK=64, global_load_lds staging, XOR-swizzled LDS.
// MODE 0: QKV epilogue (scatter to q_h/k_h/v_h; q pre-scaled by scale*log2e).
// MODE 1: out-proj epilogue (fp32 + bias).
// ---------------------------------------------------------------------------
template <int MODE>
__global__ __launch_bounds__(256, 3) void gemm_k(
    const short* __restrict__ A, const short* __restrict__ BT,
    short* __restrict__ q_h, short* __restrict__ k_h, short* __restrict__ v_h,
    float* __restrict__ outp, const float* __restrict__ bias)
{
    __shared__ __align__(16) short A_lds[128 * 64];
    __shared__ __align__(16) short B_lds[128 * 64];

    int t = threadIdx.x, wave = t >> 6, lane = t & 63;
    int quad = lane >> 4, l15 = lane & 15, h7 = l15 & 7;
    int wr = wave >> 1, wc = wave & 1;
    int m0 = blockIdx.y * 128, n0 = blockIdx.x * 128;

    f32x4 acc[4][4] = {};

    for (int kt = 0; kt < 1280; kt += 64) {
        __syncthreads();
#pragma unroll
        for (int i = 0; i < 4; i++) {
            int chunk = wave * 4 + i;
            int c = chunk * 64 + lane;
            int row = c >> 3, j = (c & 7) ^ (row & 7);
            async16(A  + (long)(m0 + row) * 1280 + kt + j * 8, A_lds + chunk * 512);
            async16(BT + (long)(n0 + row) * 1280 + kt + j * 8, B_lds + chunk * 512);
        }
        __syncthreads();

#pragma unroll
        for (int dk = 0; dk < 2; dk++) {
            bf16x8 a[4], b[4];
#pragma unroll
            for (int mi = 0; mi < 4; mi++) {
                int row = wr * 64 + mi * 16 + l15;
                a[mi] = *(const bf16x8*)&A_lds[row * 64 + ((dk * 4 + quad) ^ h7) * 8];
            }
#pragma unroll
            for (int ni = 0; ni < 4; ni++) {
                int row = wc * 64 + ni * 16 + l15;
                b[ni] = *(const bf16x8*)&B_lds[row * 64 + ((dk * 4 + quad) ^ h7) * 8];
            }
#pragma unroll
            for (int mi = 0; mi < 4; mi++)
#pragma unroll
                for (int ni = 0; ni < 4; ni++)
                    acc[mi][ni] = __builtin_amdgcn_mfma_f32_16x16x32_bf16(
                        a[mi], b[ni], acc[mi][ni], 0, 0, 0);
        }
    }

    const float SL2E = 0.07905694150420949f * 1.4426950408889634f;
#pragma unroll
    for (int mi = 0; mi < 4; mi++) {
#pragma unroll
        for (int ni = 0; ni < 4; ni++) {
#pragma unroll
            for (int r = 0; r < 4; r++) {
                int gr = m0 + wr * 64 + mi * 16 + quad * 4 + r;
                int gc = n0 + wc * 64 + ni * 16 + l15;
                float val = acc[mi][ni][r];
                if (MODE == 0) {
                    int which = gc / 1280;
                    int c1 = gc - which * 1280;
                    int hh = c1 / 160, d = c1 - hh * 160;
                    int b_ = gr >> 12, s = gr & 4095;
                    long addr = (((long)(b_ * 8 + hh)) * 4096 + s) * 160 + d;
                    if (which == 0) val *= SL2E;   // fold scale*log2e into Q
                    short* dst = (which == 0) ? q_h : (which == 1) ? k_h : v_h;
                    dst[addr] = f2bf(val);
                } else {
                    outp[(long)gr * 1280 + gc] = val + bias[gc];
                }
            }
        }
    }
}

// ---------------------------------------------------------------------------
// Flash attention, producer-consumer pipelined.
// Workgroup = (128-q-row tile, bh); wave w owns rows w*32..w*32+31 as two
// 16-row m-tiles.  Q frags in registers.
//   - K is double-buffered and prefetched ONE k-tile ahead; its DMA rides
//     across the mid-iteration barrier (raw s_barrier + vmcnt(5), not
//     __syncthreads, so it is NOT drained) and lands before the bottom
//     __syncthreads a full iteration later.
//   - V is single-buffered, issued at top of iter, consumed at PV after
//     QK+softmax (~2000 cyc) hide its latency; vmcnt(5) drains exactly V.
// Fixed-max softmax p = exp2(s-16); row-sums accumulated per-lane in regs,
// one butterfly at the end.  Last-iter K prefetch reads 64 rows past k_h --
// lands in the adjacent v_t workspace region (allocated, never consumed).
// ---------------------------------------------------------------------------
__global__ __launch_bounds__(256, 2) void flash_k(
    const short* __restrict__ q_h, const short* __restrict__ k_h,
    const short* __restrict__ v_t, short* __restrict__ attn_out)
{
    __shared__ __align__(16) short Ks128[2][64 * 128];  // K d 0..127, swizzled
    __shared__ __align__(16) short Ks32 [2][64 * 32];   // K d 128..159, swizzled
    __shared__ __align__(16) short Vs   [160 * 64];     // V^T, swizzled
    __shared__ __align__(16) short Ps   [128 * 72];     // P, pad 64->72
    // total 79,872 B -> 2 blocks/CU

    int t = threadIdx.x, wave = t >> 6, lane = t & 63;
    int quad = lane >> 4, l15 = lane & 15, h7 = l15 & 7;
    int qt = blockIdx.x;
    long bh = blockIdx.y;
    int b = (int)(bh >> 3), h = (int)(bh & 7);

    const short* kg_base = k_h + bh * 4096 * 160;

    bf16x8 qf[2][5];
#pragma unroll
    for (int mi = 0; mi < 2; mi++) {
        const short* qg = q_h + (bh * 4096 + qt * 128 + wave * 32 + mi * 16 + l15) * 160;
#pragma unroll
        for (int dk = 0; dk < 5; dk++)
            qf[mi][dk] = *(const bf16x8*)&qg[dk * 32 + quad * 8];
    }

    // preload K(0) into buffer 0
#pragma unroll
    for (int i = 0; i < 4; i++) {
        int chunk = wave * 4 + i;
        int c = chunk * 64 + lane;
        int row = c >> 4, j = (c & 15) ^ (row & 7);
        async16(kg_base + row * 160 + j * 8, &Ks128[0][chunk * 512]);
    }
    {
        int row = wave * 16 + (lane >> 2);
        int j = (lane & 3) ^ (row & 3);
        async16(kg_base + row * 160 + 128 + j * 8, &Ks32[0][wave * 512]);
    }

    f32x4 o[2][10] = {};
    float l_part[2][4] = {};
    __syncthreads();   // drains K(0) DMA for all waves

    for (int k0 = 0; k0 < 4096; k0 += 64) {
        int pb = (k0 >> 6) & 1;

        // --- issue V(k) (5/wave, oldest) ---
#pragma unroll
        for (int i = 0; i < 5; i++) {
            int chunk = wave * 5 + i;
            int c = chunk * 64 + lane;
            int row = c >> 3, j = (c & 7) ^ (row & 7);
            async16(v_t + (bh * 160 + row) * 4096 + k0 + j * 8, &Vs[chunk * 512]);
        }
        // --- issue K(k+1) prefetch into alt buffer (5/wave, newest) ---
        {
            const short* kg = kg_base + (k0 + 64) * 160;
#pragma unroll
            for (int i = 0; i < 4; i++) {
                int chunk = wave * 4 + i;
                int c = chunk * 64 + lane;
                int row = c >> 4, j = (c & 15) ^ (row & 7);
                async16(kg + row * 160 + j * 8, &Ks128[pb ^ 1][chunk * 512]);
            }
            int row = wave * 16 + (lane >> 2);
            int j = (lane & 3) ^ (row & 3);
            async16(kg + row * 160 + 128 + j * 8, &Ks32[pb ^ 1][wave * 512]);
        }

        // --- S = Q K^T from Ks[pb] (valid since last iter's barrier) ---
#pragma unroll
        for (int nt = 0; nt < 4; nt++) {
            f32x4 s0 = {}, s1 = {};
#pragma unroll
            for (int dk = 0; dk < 4; dk++) {
                bf16x8 bk = *(const bf16x8*)
                    &Ks128[pb][(nt * 16 + l15) * 128 + ((dk * 4 + quad) ^ h7) * 8];
                s0 = __builtin_amdgcn_mfma_f32_16x16x32_bf16(qf[0][dk], bk, s0, 0, 0, 0);
                s1 = __builtin_amdgcn_mfma_f32_16x16x32_bf16(qf[1][dk], bk, s1, 0, 0, 0);
            }
            {
                bf16x8 bk = *(const bf16x8*)
                    &Ks32[pb][(nt * 16 + l15) * 32 + ((quad ^ (l15 & 3)) * 8)];
                s0 = __builtin_amdgcn_mfma_f32_16x16x32_bf16(qf[0][4], bk, s0, 0, 0, 0);
                s1 = __builtin_amdgcn_mfma_f32_16x16x32_bf16(qf[1][4], bk, s1, 0, 0, 0);
            }
#pragma unroll
            for (int r = 0; r < 4; r++) {
                float p0 = exp2f(s0[r] - 16.f);
                float p1 = exp2f(s1[r] - 16.f);
                int pr0 = (wave * 32 + quad * 4 + r) * 72 + nt * 16 + l15;
                Ps[pr0]           = f2bf(p0);
                Ps[pr0 + 16 * 72] = f2bf(p1);
                l_part[0][r] += p0;
                l_part[1][r] += p1;
            }
        }

        // wait own V(k) (leaves the 5 K(k+1) issues in flight), then raw
        // barrier => all waves' V(k) landed; K prefetch rides across.
        asm volatile("s_waitcnt vmcnt(5)" ::: "memory");
        asm volatile("s_barrier" ::: "memory");

        // --- O += P V ---
#pragma unroll
        for (int ks = 0; ks < 2; ks++) {
            bf16x8 ap0 = *(const bf16x8*)&Ps[(wave * 32 + l15) * 72 + ks * 32 + quad * 8];
            bf16x8 ap1 = *(const bf16x8*)&Ps[(wave * 32 + 16 + l15) * 72 + ks * 32 + quad * 8];
#pragma unroll
            for (int ct = 0; ct < 10; ct++) {
                int row = ct * 16 + l15;
                bf16x8 bv = *(const bf16x8*)&Vs[row * 64 + (((ks * 4 + quad) ^ (row & 7)) * 8)];
                o[0][ct] = __builtin_amdgcn_mfma_f32_16x16x32_bf16(ap0, bv, o[0][ct], 0, 0, 0);
                o[1][ct] = __builtin_amdgcn_mfma_f32_16x16x32_bf16(ap1, bv, o[1][ct], 0, 0, 0);
            }
        }

        // full barrier: K(k+1) has had the whole iteration to land; protects
        // Vs/Ps overwrite next iter and publishes Ks[alt] to all waves.
        __syncthreads();
    }

#pragma unroll
    for (int mi = 0; mi < 2; mi++) {
        float inv[4];
#pragma unroll
        for (int r = 0; r < 4; r++) {
            float l = l_part[mi][r];
#pragma unroll
            for (int m = 1; m < 16; m <<= 1) l += __shfl_xor(l, m);
            inv[r] = 1.0f / l;
        }
#pragma unroll
        for (int ct = 0; ct < 10; ct++)
#pragma unroll
            for (int r = 0; r < 4; r++) {
                int gr = b * 4096 + qt * 128 + wave * 32 + mi * 16 + quad * 4 + r;
                int gc = h * 160 + ct * 16 + l15;
                attn_out[(long)gr * 1280 + gc] = f2bf(o[mi][ct][r] * inv[r]);
            }
    }
}

// ---------------------------------------------------------------------------
// Launch
// ---------------------------------------------------------------------------
extern "C" void kernel_launch(void* const* d_in, const int* in_sizes, int n_in,
                              void* d_out, int out_size, void* d_ws, size_t ws_size,
                              hipStream_t stream)
{
    const float* hs = (const float*)d_in[0];
    const float* wq = (const float*)d_in[1];
    const float* wk = (const float*)d_in[2];
    const float* wv = (const float*)d_in[3];
    const float* wo = (const float*)d_in[4];
    const float* bo = (const float*)d_in[5];
    float* out = (float*)d_out;

    // workspace layout (bytes), ~97 MB total
    char* ws = (char*)d_ws;
    short* wqkvT = (short*)(ws + 0);            // 3840*1280*2 = 9,830,400
    short* woutT = (short*)(ws + 9830400);      // 1280*1280*2 = 3,276,800
    short* q_h   = (short*)(ws + 13107200);     // 16*4096*160*2 = 20,971,520
    short* k_h   = (short*)(ws + 34078720);     // NOTE: flash prefetches 64 rows
    short* v_t   = (short*)(ws + 55050240);     //  past k_h end -> lands in v_t
    short* v_h   = (short*)(ws + 76021760);     // aliased with attn (disjoint lifetimes)
    short* attn  = v_h;
    short* hs_bf = v_t;   // hs_bf dead before v_t is born

    cast_hs<<<10240, 256, 0, stream>>>(hs, hs_bf);
    transpose_w<<<dim3(40, 40, 4), 256, 0, stream>>>(wq, wk, wv, wo, wqkvT, woutT);
    gemm_k<0><<<dim3(30, 64), 256, 0, stream>>>(hs_bf, wqkvT, q_h, k_h, v_h,
                                                nullptr, nullptr);
    transpose_v<<<dim3(128, 5, 16), 256, 0, stream>>>(v_h, v_t);
    flash_k<<<dim3(32, 16), 256, 0, stream>>>(q_h, k_h, v_t, attn);
    gemm_k<1><<<dim3(10, 64), 256, 0, stream>>>(attn, woutT, nullptr, nullptr,
                                                nullptr, out, bo);
}

// Round 5
// 482.247 us; speedup vs baseline: 1.0230x; 1.0230x over previous
//
#include <hip/hip_runtime.h>
#include <hip/hip_bf16.h>
#include <stdint.h>

// ---------------------------------------------------------------------------
// UNetAttention: hs(2,4096,1280) fp32; self-attention H=8, D=160; out fp32.
// All matmuls via mfma_f32_16x16x32_bf16 (fp32 accum).
// ---------------------------------------------------------------------------

using bf16x8 = __attribute__((ext_vector_type(8))) short;  // 8 bf16 in 4 VGPRs
using f32x4  = __attribute__((ext_vector_type(4))) float;  // MFMA C/D frag

__device__ __forceinline__ short f2bf(float f) {
    union { float f; uint32_t u; } v; v.f = f;
    uint32_t r = v.u + 0x7fffu + ((v.u >> 16) & 1u);   // RNE
    return (short)(r >> 16);
}

// async global->LDS DMA, 16B per lane.  LDS dest = wave-uniform base + lane*16.
__device__ __forceinline__ void async16(const short* g, short* l) {
    __builtin_amdgcn_global_load_lds(
        (const __attribute__((address_space(1))) void*)g,
        (__attribute__((address_space(3))) void*)l, 16, 0, 0);
}

// ---------------------------------------------------------------------------
// hs fp32 -> bf16 (row-major, for DMA-staged QKV GEMM A)
// ---------------------------------------------------------------------------
__global__ __launch_bounds__(256) void cast_hs(
    const float* __restrict__ hs, short* __restrict__ out)
{
    int i = (blockIdx.x * 256 + threadIdx.x) * 4;
    float4 v = *(const float4*)&hs[i];
    short4 s; s.x = f2bf(v.x); s.y = f2bf(v.y); s.z = f2bf(v.z); s.w = f2bf(v.w);
    *(short4*)&out[i] = s;
}

// ---------------------------------------------------------------------------
// Weight transpose+cast: w[k][n] fp32 -> wT[n][k] bf16.
// ---------------------------------------------------------------------------
__global__ __launch_bounds__(256) void transpose_w(
    const float* __restrict__ w0, const float* __restrict__ w1,
    const float* __restrict__ w2, const float* __restrict__ w3,
    short* __restrict__ wqkvT, short* __restrict__ woutT)
{
    __shared__ float tile[32][33];
    int z = blockIdx.z;
    const float* src = (z == 0) ? w0 : (z == 1) ? w1 : (z == 2) ? w2 : w3;
    short* dst = (z == 3) ? woutT : (wqkvT + (long)z * 1280 * 1280);
    int k0 = blockIdx.x * 32, n0 = blockIdx.y * 32;
    int t = threadIdx.x, r = t >> 5, c = t & 31;
#pragma unroll
    for (int i = 0; i < 4; i++)
        tile[r + i * 8][c] = src[(long)(k0 + r + i * 8) * 1280 + n0 + c];
    __syncthreads();
#pragma unroll
    for (int i = 0; i < 4; i++)
        dst[(long)(n0 + r + i * 8) * 1280 + k0 + c] = f2bf(tile[c][r + i * 8]);
}

// ---------------------------------------------------------------------------
// v_h [bh][4096][160] bf16 -> v_t [bh][160][4096] bf16
// ---------------------------------------------------------------------------
__global__ __launch_bounds__(256) void transpose_v(
    const short* __restrict__ v, short* __restrict__ vt)
{
    __shared__ short tile[32][33];
    int s0 = blockIdx.x * 32, d0 = blockIdx.y * 32;
    long bh = blockIdx.z;
    const short* src = v + bh * 4096 * 160;
    short* dst = vt + bh * 160 * 4096;
    int t = threadIdx.x, r = t >> 5, c = t & 31;
#pragma unroll
    for (int i = 0; i < 4; i++)
        tile[r + i * 8][c] = src[(s0 + r + i * 8) * 160 + d0 + c];
    __syncthreads();
#pragma unroll
    for (int i = 0; i < 4; i++)
        dst[(d0 + r + i * 8) * 4096 + s0 + c] = tile[c][r + i * 8];
}

// ---------------------------------------------------------------------------
// 128x128 MFMA GEMM, BK=64, global_load_lds staging, XOR-swizzled LDS.
// MODE 0: QKV epilogue (scatter to q_h/k_h/v_h; q pre-scaled by scale*log2e).
// MODE 1: out-proj epilogue (fp32 + bias).
// ---------------------------------------------------------------------------
template <int MODE>
__global__ __launch_bounds__(256, 3) void gemm_k(
    const short* __restrict__ A, const short* __restrict__ BT,
    short* __restrict__ q_h, short* __restrict__ k_h, short* __restrict__ v_h,
    float* __restrict__ outp, const float* __restrict__ bias)
{
    __shared__ __align__(16) short A_lds[128 * 64];
    __shared__ __align__(16) short B_lds[128 * 64];

    int t = threadIdx.x, wave = t >> 6, lane = t & 63;
    int quad = lane >> 4, l15 = lane & 15, h7 = l15 & 7;
    int wr = wave >> 1, wc = wave & 1;
    int m0 = blockIdx.y * 128, n0 = blockIdx.x * 128;

    f32x4 acc[4][4] = {};

    for (int kt = 0; kt < 1280; kt += 64) {
        __syncthreads();
#pragma unroll
        for (int i = 0; i < 4; i++) {
            int chunk = wave * 4 + i;
            int c = chunk * 64 + lane;
            int row = c >> 3, j = (c & 7) ^ (row & 7);
            async16(A  + (long)(m0 + row) * 1280 + kt + j * 8, A_lds + chunk * 512);
            async16(BT + (long)(n0 + row) * 1280 + kt + j * 8, B_lds + chunk * 512);
        }
        __syncthreads();

#pragma unroll
        for (int dk = 0; dk < 2; dk++) {
            bf16x8 a[4], b[4];
#pragma unroll
            for (int mi = 0; mi < 4; mi++) {
                int row = wr * 64 + mi * 16 + l15;
                a[mi] = *(const bf16x8*)&A_lds[row * 64 + ((dk * 4 + quad) ^ h7) * 8];
            }
#pragma unroll
            for (int ni = 0; ni < 4; ni++) {
                int row = wc * 64 + ni * 16 + l15;
                b[ni] = *(const bf16x8*)&B_lds[row * 64 + ((dk * 4 + quad) ^ h7) * 8];
            }
#pragma unroll
            for (int mi = 0; mi < 4; mi++)
#pragma unroll
                for (int ni = 0; ni < 4; ni++)
                    acc[mi][ni] = __builtin_amdgcn_mfma_f32_16x16x32_bf16(
                        a[mi], b[ni], acc[mi][ni], 0, 0, 0);
        }
    }

    const float SL2E = 0.07905694150420949f * 1.4426950408889634f;
#pragma unroll
    for (int mi = 0; mi < 4; mi++) {
#pragma unroll
        for (int ni = 0; ni < 4; ni++) {
#pragma unroll
            for (int r = 0; r < 4; r++) {
                int gr = m0 + wr * 64 + mi * 16 + quad * 4 + r;
                int gc = n0 + wc * 64 + ni * 16 + l15;
                float val = acc[mi][ni][r];
                if (MODE == 0) {
                    int which = gc / 1280;
                    int c1 = gc - which * 1280;
                    int hh = c1 / 160, d = c1 - hh * 160;
                    int b_ = gr >> 12, s = gr & 4095;
                    long addr = (((long)(b_ * 8 + hh)) * 4096 + s) * 160 + d;
                    if (which == 0) val *= SL2E;   // fold scale*log2e into Q
                    short* dst = (which == 0) ? q_h : (which == 1) ? k_h : v_h;
                    dst[addr] = f2bf(val);
                } else {
                    outp[(long)gr * 1280 + gc] = val + bias[gc];
                }
            }
        }
    }
}

// ---------------------------------------------------------------------------
// Flash attention (R3 structure + XCD-pinned scheduling).
// Grid = dim3(16=bh, 32=qt): linear block id = bh + 16*qt, so round-robin
// id%8 pins all 32 q-tiles of one bh to XCD bh%8.  Those 32 wgs march through
// the same K/V k0 sequence nearly in lockstep -> instantaneous working set
// ~100 KB, served from the XCD-local 4 MB L2 (34.5 TB/s) instead of LLC/HBM
// (the measured 5.5 TB/s staging wall of R3/R4).
// Wave w owns rows w*32..w*32+31 as two 16-row m-tiles (register-blocked).
// Q frags in registers.  Fixed-max softmax p = exp2(s-16) (o/l division
// makes the fixed max exact).  Row-sums via all-ones V^T row (ct=10 tile).
// ---------------------------------------------------------------------------
__global__ __launch_bounds__(256, 2) void flash_k(
    const short* __restrict__ q_h, const short* __restrict__ k_h,
    const short* __restrict__ v_t, short* __restrict__ attn_out)
{
    __shared__ __align__(16) short Ks128[64 * 128];  // K d 0..127, swizzled
    __shared__ __align__(16) short Ks32 [64 * 32];   // K d 128..159, swizzled
    __shared__ __align__(16) short Vs   [176 * 64];  // V^T, swizzled; row 160=ones
    __shared__ __align__(16) short Ps   [128 * 72];  // P, pad 64->72
    // total 60.9 KB -> 2 blocks/CU (grid also gives exactly 2/CU)

    int t = threadIdx.x, wave = t >> 6, lane = t & 63;
    int quad = lane >> 4, l15 = lane & 15, h7 = l15 & 7;
    int qt = blockIdx.y;           // q-tile: slow grid dim
    long bh = blockIdx.x;          // bh: fast grid dim -> XCD = bh % 8
    int b = (int)(bh >> 3), h = (int)(bh & 7);

    bf16x8 qf[2][5];
#pragma unroll
    for (int mi = 0; mi < 2; mi++) {
        const short* qg = q_h + (bh * 4096 + qt * 128 + wave * 32 + mi * 16 + l15) * 160;
#pragma unroll
        for (int dk = 0; dk < 5; dk++)
            qf[mi][dk] = *(const bf16x8*)&qg[dk * 32 + quad * 8];
    }
    {   // Vs rows 160..175: row 160 = bf16(1.0), rest zero (never re-staged)
        short v1 = (t < 16) ? (short)0x3F80 : (short)0;
        short4 s4 = { v1, v1, v1, v1 };
        *(short4*)&Vs[160 * 64 + t * 4] = s4;
    }

    f32x4 o[2][11] = {};   // o[mi][10] = row-sum accumulator (ones-row tile)

    for (int k0 = 0; k0 < 4096; k0 += 64) {
        __syncthreads();
        const short* kg = k_h + (bh * 4096 + k0) * 160;
#pragma unroll
        for (int i = 0; i < 4; i++) {          // Ks128: 16 issues of 1KB
            int chunk = wave * 4 + i;
            int c = chunk * 64 + lane;
            int row = c >> 4, j = (c & 15) ^ (row & 7);
            async16(kg + row * 160 + j * 8, Ks128 + chunk * 512);
        }
        {                                       // Ks32: 4 issues (1/wave)
            int row = wave * 16 + (lane >> 2);
            int j = (lane & 3) ^ (row & 3);
            async16(kg + row * 160 + 128 + j * 8, Ks32 + wave * 512);
        }
#pragma unroll
        for (int i = 0; i < 5; i++) {          // Vs rows 0..159: 20 issues
            int chunk = wave * 5 + i;
            int c = chunk * 64 + lane;
            int row = c >> 3, j = (c & 7) ^ (row & 7);
            async16(v_t + (bh * 160 + row) * 4096 + k0 + j * 8, Vs + chunk * 512);
        }
        __syncthreads();

        // S = Q K^T per n-tile, then p = exp2(s-16) straight to Ps
#pragma unroll
        for (int nt = 0; nt < 4; nt++) {
            f32x4 s0 = {}, s1 = {};
#pragma unroll
            for (int dk = 0; dk < 4; dk++) {
                bf16x8 bk = *(const bf16x8*)
                    &Ks128[(nt * 16 + l15) * 128 + ((dk * 4 + quad) ^ h7) * 8];
                s0 = __builtin_amdgcn_mfma_f32_16x16x32_bf16(qf[0][dk], bk, s0, 0, 0, 0);
                s1 = __builtin_amdgcn_mfma_f32_16x16x32_bf16(qf[1][dk], bk, s1, 0, 0, 0);
            }
            {
                bf16x8 bk = *(const bf16x8*)
                    &Ks32[(nt * 16 + l15) * 32 + ((quad ^ (l15 & 3)) * 8)];
                s0 = __builtin_amdgcn_mfma_f32_16x16x32_bf16(qf[0][4], bk, s0, 0, 0, 0);
                s1 = __builtin_amdgcn_mfma_f32_16x16x32_bf16(qf[1][4], bk, s1, 0, 0, 0);
            }
#pragma unroll
            for (int r = 0; r < 4; r++) {
                int pr0 = (wave * 32 + quad * 4 + r) * 72 + nt * 16 + l15;
                Ps[pr0]            = f2bf(exp2f(s0[r] - 16.f));
                Ps[pr0 + 16 * 72]  = f2bf(exp2f(s1[r] - 16.f));
            }
        }

        // O += P V  (Ps rows are wave-private; compiler's lgkmcnt covers RAW)
#pragma unroll
        for (int ks = 0; ks < 2; ks++) {
            bf16x8 ap0 = *(const bf16x8*)&Ps[(wave * 32 + l15) * 72 + ks * 32 + quad * 8];
            bf16x8 ap1 = *(const bf16x8*)&Ps[(wave * 32 + 16 + l15) * 72 + ks * 32 + quad * 8];
#pragma unroll
            for (int ct = 0; ct < 11; ct++) {
                int row = ct * 16 + l15;
                bf16x8 bv = *(const bf16x8*)&Vs[row * 64 + (((ks * 4 + quad) ^ (row & 7)) * 8)];
                o[0][ct] = __builtin_amdgcn_mfma_f32_16x16x32_bf16(ap0, bv, o[0][ct], 0, 0, 0);
                o[1][ct] = __builtin_amdgcn_mfma_f32_16x16x32_bf16(ap1, bv, o[1][ct], 0, 0, 0);
            }
        }
    }

#pragma unroll
    for (int mi = 0; mi < 2; mi++) {
        float inv[4];
#pragma unroll
        for (int r = 0; r < 4; r++)
            inv[r] = 1.0f / __shfl(o[mi][10][r], (lane & 48));  // l at l15==0 of quad
#pragma unroll
        for (int ct = 0; ct < 10; ct++)
#pragma unroll
            for (int r = 0; r < 4; r++) {
                int gr = b * 4096 + qt * 128 + wave * 32 + mi * 16 + quad * 4 + r;
                int gc = h * 160 + ct * 16 + l15;
                attn_out[(long)gr * 1280 + gc] = f2bf(o[mi][ct][r] * inv[r]);
            }
    }
}

// ---------------------------------------------------------------------------
// Launch
// ---------------------------------------------------------------------------
extern "C" void kernel_launch(void* const* d_in, const int* in_sizes, int n_in,
                              void* d_out, int out_size, void* d_ws, size_t ws_size,
                              hipStream_t stream)
{
    const float* hs = (const float*)d_in[0];
    const float* wq = (const float*)d_in[1];
    const float* wk = (const float*)d_in[2];
    const float* wv = (const float*)d_in[3];
    const float* wo = (const float*)d_in[4];
    const float* bo = (const float*)d_in[5];
    float* out = (float*)d_out;

    // workspace layout (bytes), ~97 MB total
    char* ws = (char*)d_ws;
    short* wqkvT = (short*)(ws + 0);            // 3840*1280*2 = 9,830,400
    short* woutT = (short*)(ws + 9830400);      // 1280*1280*2 = 3,276,800
    short* q_h   = (short*)(ws + 13107200);     // 16*4096*160*2 = 20,971,520
    short* k_h   = (short*)(ws + 34078720);
    short* v_t   = (short*)(ws + 55050240);     // also hs_bf before transpose_v
    short* v_h   = (short*)(ws + 76021760);     // aliased with attn (disjoint lifetimes)
    short* attn  = v_h;
    short* hs_bf = v_t;   // hs_bf dead before v_t is born

    cast_hs<<<10240, 256, 0, stream>>>(hs, hs_bf);
    transpose_w<<<dim3(40, 40, 4), 256, 0, stream>>>(wq, wk, wv, wo, wqkvT, woutT);
    gemm_k<0><<<dim3(30, 64), 256, 0, stream>>>(hs_bf, wqkvT, q_h, k_h, v_h,
                                                nullptr, nullptr);
    transpose_v<<<dim3(128, 5, 16), 256, 0, stream>>>(v_h, v_t);
    flash_k<<<dim3(16, 32), 256, 0, stream>>>(q_h, k_h, v_t, attn);
    gemm_k<1><<<dim3(10, 64), 256, 0, stream>>>(attn, woutT, nullptr, nullptr,
                                                nullptr, out, bo);
}